// Round 2
// baseline (484.106 us; speedup 1.0000x reference)
//
#include <hip/hip_runtime.h>

// AbstractLinear: y = x @ W.T + b  (256x8192x8192, bf16 MFMA)
//                 IBP bounds fused on W registers (fp32):
//                 P = W@(l+h), R = |W|@(h-l); low=.5(P-R)+b, high=.5(P+R)+b
// R6: traffic-bound redesign. R4/R5 falsified latency theory: dur always
//     = FETCH/2.35 TB/s regardless of schedule. New structure makes W a
//     read-once linear stream: 256 blocks x 8 waves (2 n-waves x 4
//     k-quarters), each wave owns 16 W rows x 2048 k, streamed global->reg
//     ->bf16 frag. x pre-converted to bf16 fragment-ordered (prep kernel,
//     d_ws) so A-frags are single dwordx4 loads; no LDS staging, no main-
//     loop barriers. Cross-kh y-reduction via LDS epilogue; bounds via
//     small LDS buffer. W fetch = 256 MB exactly.
#define M_TOTAL 256
#define N_TOTAL 8192
#define K_TOTAL 8192

typedef __attribute__((ext_vector_type(4))) float f32x4;
typedef __attribute__((ext_vector_type(8))) short s16x8;
typedef __attribute__((ext_vector_type(4))) int   i32x4;
typedef unsigned short ushort_t;

// pack two fp32 -> two bf16 (truncation) in one v_perm_b32 (low = a, high = b)
__device__ __forceinline__ int pk(float a, float b) {
    return (int)__builtin_amdgcn_perm(__float_as_uint(b), __float_as_uint(a), 0x07060302u);
}

// ---------------- prep: x fp32 -> bf16 fragment-ordered; lh/hl precompute ----
// xpre chunk layout: chunk id = (kt*8 + c)*256 + row  holds
//   bf16(x[row][kt*64 + c*8 .. +8]), 16 B per chunk, dst-contiguous stores.
__global__ __launch_bounds__(256)
void prep_kernel(const float* __restrict__ x,
                 const float* __restrict__ low,
                 const float* __restrict__ high,
                 ushort_t* __restrict__ xpre,
                 float* __restrict__ lh,
                 float* __restrict__ hl) {
    const int bx = blockIdx.x, t = threadIdx.x;
    if (bx < 1024) {
        const int id  = bx * 256 + t;   // 262144 chunks
        const int kt  = id >> 11;
        const int c   = (id >> 8) & 7;
        const int row = id & 255;
        const float* src = x + (size_t)row * K_TOTAL + kt * 64 + c * 8;
        f32x4 s0 = *(const f32x4*)(src);
        f32x4 s1 = *(const f32x4*)(src + 4);
        i32x4 bi;
        bi[0] = pk(s0[0], s0[1]); bi[1] = pk(s0[2], s0[3]);
        bi[2] = pk(s1[0], s1[1]); bi[3] = pk(s1[2], s1[3]);
        *(i32x4*)(xpre + (size_t)id * 8) = bi;
    } else {
        const int i = (bx - 1024) * 256 + t;   // 32 blocks x 256 = 8192
        float lo = low[i], hi = high[i];
        lh[i] = lo + hi;
        hl[i] = hi - lo;
    }
}

// ---------------- main ----------------
__global__ __launch_bounds__(512)
void abstract_linear_kernel(const ushort_t* __restrict__ xpre,
                            const float* __restrict__ W,
                            const float* __restrict__ lh,
                            const float* __restrict__ hl,
                            const float* __restrict__ bias,
                            float* __restrict__ out) {
    __shared__ float ybuf[M_TOTAL * 32];   // 32 KB cross-kh y reduction
    __shared__ float pbuf[4 * 32];
    __shared__ float rbuf[4 * 32];

    const int t    = threadIdx.x;
    const int w    = t >> 6;
    const int nw   = w & 1;        // n-half within block (16 cols each)
    const int kh   = w >> 1;       // k-quarter 0..3
    const int lane = t & 63;
    const int l15  = lane & 15;
    const int lq   = lane >> 4;
    const int n0   = blockIdx.x * 32;
    const int nl   = nw * 16 + l15;

    f32x4 acc[16];
#pragma unroll
    for (int i = 0; i < 16; ++i) acc[i] = (f32x4){0.f, 0.f, 0.f, 0.f};

    float P = 0.f, R = 0.f;

    // per-wave streams: W rows n0+nl, k in [kh*2048, kh*2048+2048), lane owns
    // k-chunk lq*8 within each 32-k step. A-frags from xpre, fragment-ordered.
    const float*    wp  = W  + (size_t)(n0 + nl) * K_TOTAL + kh * 2048 + lq * 8;
    const float*    lhp = lh + kh * 2048 + lq * 8;
    const float*    hlp = hl + kh * 2048 + lq * 8;
    const ushort_t* ap  = xpre + (size_t)kh * 64 * 8192 + lq * 2048 + l15 * 8;

    // 2-slot W / lh / hl register pipeline (one 32-k step ahead)
    f32x4 wA[2], wB[2], lA[2], lB[2], hA[2], hB[2];

    auto ldW = [&](int sl, int st) {
        wA[sl] = *(const f32x4*)(wp  + st * 32);
        wB[sl] = *(const f32x4*)(wp  + st * 32 + 4);
        lA[sl] = *(const f32x4*)(lhp + st * 32);
        lB[sl] = *(const f32x4*)(lhp + st * 32 + 4);
        hA[sl] = *(const f32x4*)(hlp + st * 32);
        hB[sl] = *(const f32x4*)(hlp + st * 32 + 4);
    };

    auto compute = [&](int sl, int st) {
        f32x4 w0 = wA[sl], w1 = wB[sl];
        i32x4 bi;
        bi[0] = pk(w0[0], w0[1]); bi[1] = pk(w0[2], w0[3]);
        bi[2] = pk(w1[0], w1[1]); bi[3] = pk(w1[2], w1[3]);
        s16x8 bf = *(s16x8*)&bi;
        f32x4 l0 = lA[sl], l1 = lB[sl], h0 = hA[sl], h1 = hB[sl];
#pragma unroll
        for (int e = 0; e < 4; ++e) {
            P = fmaf(w0[e], l0[e], P);
            P = fmaf(w1[e], l1[e], P);
            R = fmaf(fabsf(w0[e]), h0[e], R);
            R = fmaf(fabsf(w1[e]), h1[e], R);
        }
        const ushort_t* a_st = ap + (size_t)st * 8192;
#pragma unroll
        for (int half = 0; half < 2; ++half) {
            s16x8 af[8];
#pragma unroll
            for (int mi = 0; mi < 8; ++mi)
                af[mi] = *(const s16x8*)(a_st + (half * 8 + mi) * 128);
#pragma unroll
            for (int mi = 0; mi < 8; ++mi)
                acc[half * 8 + mi] = __builtin_amdgcn_mfma_f32_16x16x32_bf16(
                    af[mi], bf, acc[half * 8 + mi], 0, 0, 0);
        }
    };

    // 64 k32-steps per wave, no barriers, W stream purely sequential
    ldW(0, 0);
    for (int st = 0; st < 64; st += 2) {
        ldW(1, st + 1);
        compute(0, st);
        if (st < 62) ldW(0, st + 2);
        compute(1, st + 1);
    }

    // ---- bounds: reduce over the 4 lq lanes holding the same W row ----
    P += __shfl_xor(P, 16); P += __shfl_xor(P, 32);
    R += __shfl_xor(R, 16); R += __shfl_xor(R, 32);
    if (lane < 16) {
        pbuf[kh * 32 + nl] = P;
        rbuf[kh * 32 + nl] = R;
    }

    const float bv = bias[n0 + nl];

    // ---- y: cross-kh reduction through LDS, then store with bias ----
    // C/D layout: col = lane&15 -> n, row = lq*4 + e -> m (within 16x16 frag)
    for (int rr = 0; rr < 4; ++rr) {
        __syncthreads();
        if (kh == rr) {
#pragma unroll
            for (int mi = 0; mi < 16; ++mi) {
#pragma unroll
                for (int e = 0; e < 4; ++e) {
                    int m = mi * 16 + lq * 4 + e;
                    int idx = m * 32 + nl;
                    float v = acc[mi][e];
                    if (rr > 0) v += ybuf[idx];
                    if (rr < 3) ybuf[idx] = v;
                    else out[(size_t)m * N_TOTAL + n0 + nl] = v + bv;
                }
            }
        }
    }
    __syncthreads();

    // ---- bounds epilogue: one wave sums the 4 k-quarters ----
    if (w == 0 && lane < 32) {
        float Ps = pbuf[lane] + pbuf[32 + lane] + pbuf[64 + lane] + pbuf[96 + lane];
        float Rs = rbuf[lane] + rbuf[32 + lane] + rbuf[64 + lane] + rbuf[96 + lane];
        float bb = bias[n0 + lane];
        out[(size_t)M_TOTAL * N_TOTAL + n0 + lane]           = 0.5f * (Ps - Rs) + bb;
        out[(size_t)M_TOTAL * N_TOTAL + N_TOTAL + n0 + lane] = 0.5f * (Ps + Rs) + bb;
    }
}

extern "C" void kernel_launch(void* const* d_in, const int* in_sizes, int n_in,
                              void* d_out, int out_size, void* d_ws, size_t ws_size,
                              hipStream_t stream) {
    const float* x    = (const float*)d_in[0];
    const float* low  = (const float*)d_in[1];
    const float* high = (const float*)d_in[2];
    const float* W    = (const float*)d_in[3];
    const float* b    = (const float*)d_in[4];
    float* out = (float*)d_out;

    // workspace: xpre 4 MB (bf16 fragment-ordered x) + lh 32 KB + hl 32 KB
    ushort_t* xpre = (ushort_t*)d_ws;
    float* lh = (float*)((char*)d_ws + (size_t)M_TOTAL * K_TOTAL * 2);
    float* hl = lh + K_TOTAL;

    hipLaunchKernelGGL(prep_kernel, dim3(1056), dim3(256), 0, stream,
                       x, low, high, xpre, lh, hl);
    hipLaunchKernelGGL(abstract_linear_kernel, dim3(N_TOTAL / 32), dim3(512), 0, stream,
                       xpre, W, lh, hl, b, out);
}